// Round 4
// baseline (544.122 us; speedup 1.0000x reference)
//
#include <hip/hip_runtime.h>
#include <hip/hip_fp16.h>
#include <math.h>
#include <type_traits>

typedef _Float16 half8 __attribute__((ext_vector_type(8)));
typedef float floatx4 __attribute__((ext_vector_type(4)));

// ---------------- degree count ----------------
__global__ void deg_count_kernel(const int* __restrict__ row, int* __restrict__ degi, int E) {
    int g = blockIdx.x * blockDim.x + threadIdx.x;
    if (g < E) atomicAdd(&degi[row[g]], 1);
}

// ---------------- per-node GSO coefficient helper ----------------
__device__ __forceinline__ float pow_z(float d, float e) {
    float p = powf(d, e);
    return isinf(p) ? 0.0f : p;   // reference zeroes inf from 0**negative
}

__device__ __forceinline__ void gso_coeff(float deg, const float* __restrict__ p1,
                                          const float* __restrict__ p2,
                                          float4* cf, float* ws) {
    float m1a = p1[0], m2a = p1[1], m3a = p1[2], e1a = p1[3], e2a = p1[4], e3a = p1[5], aa = p1[6];
    float m1b = p2[0], m2b = p2[1], m3b = p2[2], e1b = p2[3], e2b = p2[4], e3b = p2[5], ab = p2[6];
    float d1 = deg + aa, d2 = deg + ab;
    float pa1 = pow_z(d1, e1a), pa2 = pow_z(d1, e2a), pa3 = pow_z(d1, e3a);
    float pb1 = pow_z(d2, e1b), pb2 = pow_z(d2, e2b), pb3 = pow_z(d2, e3b);
    *cf = make_float4(m2a * pa2, pa3, m2b * pb2, pb3);
    *ws = m1a * pa1 + m2a * pa2 * pa3 + m3a
        + m1b * pb1 + m2b * pb2 * pb3 + m3b;
}

// ---------------- fused: block scan of degrees + GSO coefficients ----------------
__global__ void scan_block_kernel(const int* __restrict__ degi, int* __restrict__ rowptr,
                                  int* __restrict__ blocksum,
                                  const float* __restrict__ p1, const float* __restrict__ p2,
                                  float4* __restrict__ coeff, float* __restrict__ wself, int n) {
    __shared__ int sums[256];
    int tid = threadIdx.x;
    int base = blockIdx.x * 1024 + tid * 4;
    int d0 = (base + 0 < n) ? degi[base + 0] : 0;
    int d1 = (base + 1 < n) ? degi[base + 1] : 0;
    int d2 = (base + 2 < n) ? degi[base + 2] : 0;
    int d3 = (base + 3 < n) ? degi[base + 3] : 0;
    int s0 = d0, s1 = s0 + d1, s2 = s1 + d2, s3 = s2 + d3;
    sums[tid] = s3;
    __syncthreads();
    for (int off = 1; off < 256; off <<= 1) {
        int v = (tid >= off) ? sums[tid - off] : 0;
        __syncthreads();
        sums[tid] += v;
        __syncthreads();
    }
    int excl = sums[tid] - s3;
    if (base + 0 < n) rowptr[base + 1] = excl + s0;
    if (base + 1 < n) rowptr[base + 2] = excl + s1;
    if (base + 2 < n) rowptr[base + 3] = excl + s2;
    if (base + 3 < n) rowptr[base + 4] = excl + s3;
    if (tid == 255) blocksum[blockIdx.x] = sums[255];
    // fused per-node GSO coefficients (degrees already in registers)
    int dd[4] = {d0, d1, d2, d3};
#pragma unroll
    for (int u = 0; u < 4; ++u) {
        if (base + u < n) {
            float4 cf; float ws;
            gso_coeff((float)dd[u], p1, p2, &cf, &ws);
            coeff[base + u] = cf;
            wself[base + u] = ws;
        }
    }
}

__global__ void scan_tops_kernel(const int* __restrict__ blocksum, int* __restrict__ blockoff, int nb) {
    __shared__ int s[128];
    int tid = threadIdx.x;
    int v = (tid < nb) ? blocksum[tid] : 0;
    s[tid] = v;
    __syncthreads();
    for (int off = 1; off < 128; off <<= 1) {
        int u = (tid >= off) ? s[tid - off] : 0;
        __syncthreads();
        s[tid] += u;
        __syncthreads();
    }
    if (tid < nb) blockoff[tid] = s[tid] - v;
}

__global__ void scan_add_kernel(int* __restrict__ rowptr, const int* __restrict__ blockoff, int n) {
    int g = blockIdx.x * blockDim.x + threadIdx.x;
    if (g == 0) rowptr[0] = 0;
    if (g < n) rowptr[g + 1] += blockoff[g >> 10];
}

// ---------------- CSR fill: destination-bucketed scatter ----------------
// 8 row-buckets (row >> shift). Block j handles bucket j&7 and grid-strides the
// whole edge list, keeping only its bucket's edges. Same-bucket blocks land on
// the same XCD under round-robin dispatch -> each bucket's epack region (~1.6MB)
// stays in one XCD L2, lines fill completely before writeback (kills the
// 64B-per-8B-store write amplification). Correctness does NOT depend on the
// XCD mapping (coverage is blockIdx arithmetic only).
#define FILL_C 160   // chunks; grid = 8*FILL_C blocks
__global__ __launch_bounds__(256) void fill_edges_kernel(
        const int* __restrict__ row, const int* __restrict__ col,
        const int* __restrict__ rowptr, int* __restrict__ cursor,
        const float4* __restrict__ coeff, int2* __restrict__ epack,
        int E, int N, int shift) {
    int b = blockIdx.x & 7;
    if ((b << shift) >= N) return;            // empty bucket
    int tb = (blockIdx.x >> 3) * 256 + threadIdx.x;
    int stride = (gridDim.x >> 3) * 256;
    for (int e = tb; e < E; e += stride) {
        int r = row[e];
        if ((r >> shift) == b) {
            int c = col[e];
            int pos = rowptr[r] + atomicAdd(&cursor[r], 1);
            float4 cr = coeff[r], cc = coeff[c];
            float w = cr.x * cc.y + cr.z * cc.w;
            epack[pos] = make_int2(c, __float_as_int(w));
        }
    }
}

// ---------------- W convert + transpose (all three in one launch) ----------------
__global__ void convert_w_all(const float* __restrict__ W1, const float* __restrict__ W2,
                              const float* __restrict__ W3, _Float16* __restrict__ Wt1,
                              _Float16* __restrict__ Wt2, _Float16* __restrict__ Wt3) {
    int g = blockIdx.x * blockDim.x + threadIdx.x;
    if (g < 16384) {
        int k = g >> 7, n = g & 127;
        Wt1[n * 128 + k] = (_Float16)W1[g];
    } else if (g < 32768) {
        int h = g - 16384; int k = h >> 7, n = h & 127;
        Wt2[n * 128 + k] = (_Float16)W2[h];
    } else if (g < 40960) {
        int h = g - 32768; int k = h >> 6, n = h & 63;
        Wt3[n * 128 + k] = (_Float16)W3[h];
    }
}

// ---------------- MFMA GEMM: A[n x 128] @ W[128 x TN] -> C[n x TN] fp16 ----------------
template<int TN, typename AT>
__global__ __launch_bounds__(256) void gemm_mfma(const AT* __restrict__ A,
        const _Float16* __restrict__ Wt,   // [TN][128] pre-transposed fp16
        _Float16* __restrict__ C, int n) {
    constexpr int K = 128;
    constexpr int TM = 64;
    constexpr int LDK = K + 8;             // pad 8 halves (16B)
    __shared__ _Float16 As[TM][LDK];
    __shared__ _Float16 Bs[TN][LDK];

    int tid = threadIdx.x;
    int wave = tid >> 6, lane = tid & 63;
    int q = lane >> 4, t = lane & 15;
    int rowbase = blockIdx.x * TM;

    if constexpr (std::is_same<AT, float>::value) {
        for (int i = tid; i < TM * K / 4; i += 256) {
            int r = i >> 5;
            int kc = (i & 31) * 4;
            int rr = rowbase + r;
            float4 v = make_float4(0.f, 0.f, 0.f, 0.f);
            if (rr < n) v = *(const float4*)&A[(size_t)rr * K + kc];
            As[r][kc + 0] = (_Float16)v.x;
            As[r][kc + 1] = (_Float16)v.y;
            As[r][kc + 2] = (_Float16)v.z;
            As[r][kc + 3] = (_Float16)v.w;
        }
    } else {
        for (int i = tid; i < TM * K / 8; i += 256) {
            int r = i >> 4;
            int kc = (i & 15) * 8;
            int rr = rowbase + r;
            uint4 v = make_uint4(0u, 0u, 0u, 0u);
            if (rr < n) v = *(const uint4*)&A[(size_t)rr * K + kc];
            *(uint4*)&As[r][kc] = v;
        }
    }
    for (int i = tid; i < TN * K / 8; i += 256) {
        int nr = i >> 4;
        int kc = (i & 15) * 8;
        *(uint4*)&Bs[nr][kc] = *(const uint4*)&Wt[(size_t)nr * K + kc];
    }
    __syncthreads();

    int m0 = wave * 16;
    floatx4 acc[TN / 16];
#pragma unroll
    for (int nt = 0; nt < TN / 16; ++nt) acc[nt] = (floatx4){0.f, 0.f, 0.f, 0.f};

#pragma unroll
    for (int kk = 0; kk < K; kk += 32) {
        half8 a = *(const half8*)&As[m0 + t][kk + q * 8];
#pragma unroll
        for (int nt = 0; nt < TN / 16; ++nt) {
            half8 b = *(const half8*)&Bs[nt * 16 + t][kk + q * 8];
            acc[nt] = __builtin_amdgcn_mfma_f32_16x16x32_f16(a, b, acc[nt], 0, 0, 0);
        }
    }

#pragma unroll
    for (int nt = 0; nt < TN / 16; ++nt) {
#pragma unroll
        for (int r = 0; r < 4; ++r) {
            int rr = rowbase + m0 + q * 4 + r;
            if (rr < n) C[(size_t)rr * TN + nt * 16 + t] = (_Float16)acc[nt][r];
        }
    }
}

// ---------------- CSR aggregation, D=128, fp16 in / fp16 out, relu ----------------
__global__ __launch_bounds__(256) void agg128_kernel(const __half2* __restrict__ H,
        const int* __restrict__ rowptr, const int2* __restrict__ epack,
        const float* __restrict__ wself, const float* __restrict__ bias,
        __half2* __restrict__ out, int n) {
    int node = blockIdx.x * 4 + (threadIdx.x >> 6);
    if (node >= n) return;
    int lane = threadIdx.x & 63;
    int start = rowptr[node], end = rowptr[node + 1];
    float ws = wself[node];
    float2 hs = __half22float2(H[(size_t)node * 64 + lane]);
    float ax = ws * hs.x, ay = ws * hs.y;
    int e = start;
    for (; e + 8 <= end; e += 8) {
        int2 p0 = epack[e + 0], p1 = epack[e + 1], p2 = epack[e + 2], p3 = epack[e + 3];
        int2 p4 = epack[e + 4], p5 = epack[e + 5], p6 = epack[e + 6], p7 = epack[e + 7];
        __half2 h0 = H[(size_t)p0.x * 64 + lane];
        __half2 h1 = H[(size_t)p1.x * 64 + lane];
        __half2 h2 = H[(size_t)p2.x * 64 + lane];
        __half2 h3 = H[(size_t)p3.x * 64 + lane];
        __half2 h4 = H[(size_t)p4.x * 64 + lane];
        __half2 h5 = H[(size_t)p5.x * 64 + lane];
        __half2 h6 = H[(size_t)p6.x * 64 + lane];
        __half2 h7 = H[(size_t)p7.x * 64 + lane];
        float2 f0 = __half22float2(h0), f1 = __half22float2(h1);
        float2 f2 = __half22float2(h2), f3 = __half22float2(h3);
        float2 f4 = __half22float2(h4), f5 = __half22float2(h5);
        float2 f6 = __half22float2(h6), f7 = __half22float2(h7);
        float w0 = __int_as_float(p0.y), w1 = __int_as_float(p1.y);
        float w2 = __int_as_float(p2.y), w3 = __int_as_float(p3.y);
        float w4 = __int_as_float(p4.y), w5 = __int_as_float(p5.y);
        float w6 = __int_as_float(p6.y), w7 = __int_as_float(p7.y);
        ax += w0 * f0.x + w1 * f1.x + w2 * f2.x + w3 * f3.x
            + w4 * f4.x + w5 * f5.x + w6 * f6.x + w7 * f7.x;
        ay += w0 * f0.y + w1 * f1.y + w2 * f2.y + w3 * f3.y
            + w4 * f4.y + w5 * f5.y + w6 * f6.y + w7 * f7.y;
    }
    for (; e < end; ++e) {
        int2 pe = epack[e];
        float w = __int_as_float(pe.y);
        float2 f = __half22float2(H[(size_t)pe.x * 64 + lane]);
        ax += w * f.x; ay += w * f.y;
    }
    float2 b = *(const float2*)&bias[2 * lane];
    float vx = fmaxf(ax + b.x, 0.0f);
    float vy = fmaxf(ay + b.y, 0.0f);
    out[(size_t)node * 64 + lane] = __floats2half2_rn(vx, vy);
}

// ---------------- CSR aggregation, D=64, fp16 in / fp32 out, no relu ----------------
__global__ __launch_bounds__(256) void agg64_kernel(const __half* __restrict__ H,
        const int* __restrict__ rowptr, const int2* __restrict__ epack,
        const float* __restrict__ wself, const float* __restrict__ bias,
        float* __restrict__ out, int n) {
    int node = blockIdx.x * 4 + (threadIdx.x >> 6);
    if (node >= n) return;
    int lane = threadIdx.x & 63;
    int start = rowptr[node], end = rowptr[node + 1];
    float ws = wself[node];
    float acc = ws * __half2float(H[(size_t)node * 64 + lane]);
    int e = start;
    for (; e + 8 <= end; e += 8) {
        int2 p0 = epack[e + 0], p1 = epack[e + 1], p2 = epack[e + 2], p3 = epack[e + 3];
        int2 p4 = epack[e + 4], p5 = epack[e + 5], p6 = epack[e + 6], p7 = epack[e + 7];
        float f0 = __half2float(H[(size_t)p0.x * 64 + lane]);
        float f1 = __half2float(H[(size_t)p1.x * 64 + lane]);
        float f2 = __half2float(H[(size_t)p2.x * 64 + lane]);
        float f3 = __half2float(H[(size_t)p3.x * 64 + lane]);
        float f4 = __half2float(H[(size_t)p4.x * 64 + lane]);
        float f5 = __half2float(H[(size_t)p5.x * 64 + lane]);
        float f6 = __half2float(H[(size_t)p6.x * 64 + lane]);
        float f7 = __half2float(H[(size_t)p7.x * 64 + lane]);
        acc += __int_as_float(p0.y) * f0 + __int_as_float(p1.y) * f1
             + __int_as_float(p2.y) * f2 + __int_as_float(p3.y) * f3
             + __int_as_float(p4.y) * f4 + __int_as_float(p5.y) * f5
             + __int_as_float(p6.y) * f6 + __int_as_float(p7.y) * f7;
    }
    for (; e < end; ++e) {
        int2 pe = epack[e];
        acc += __int_as_float(pe.y) * __half2float(H[(size_t)pe.x * 64 + lane]);
    }
    out[(size_t)node * 64 + lane] = acc + bias[lane];
}

// ---------------- launch ----------------
extern "C" void kernel_launch(void* const* d_in, const int* in_sizes, int n_in,
                              void* d_out, int out_size, void* d_ws, size_t ws_size,
                              hipStream_t stream) {
    const float* x  = (const float*)d_in[0];
    const int*   ei = (const int*)d_in[1];
    const float* W1 = (const float*)d_in[2];
    const float* b1 = (const float*)d_in[3];
    const float* W2 = (const float*)d_in[4];
    const float* b2 = (const float*)d_in[5];
    const float* W3 = (const float*)d_in[6];
    const float* b3 = (const float*)d_in[7];
    const float* p1 = (const float*)d_in[8];
    const float* p2 = (const float*)d_in[9];

    const int N = in_sizes[0] / 128;
    const int E = in_sizes[1] / 2;
    const int* row = ei;
    const int* col = ei + E;

    // bucket shift: smallest s with (N-1)>>s <= 7  (N=100000 -> 14)
    int shift = 0;
    while (((N - 1) >> shift) > 7) shift++;

    char* p = (char*)d_ws;
    auto alloc = [&](size_t bytes) -> void* {
        void* q = (void*)p;
        p += (bytes + 255) & ~(size_t)255;
        return q;
    };
    int*      degi     = (int*)alloc((size_t)N * 4);
    int*      cursor   = (int*)alloc((size_t)N * 4);     // contiguous with degi for one memset
    int*      rowptr   = (int*)alloc((size_t)(N + 1) * 4);
    const int NBLK     = (N + 1023) / 1024;              // 98 for N=100000
    int*      blocksum = (int*)alloc((size_t)NBLK * 4);
    int*      blockoff = (int*)alloc((size_t)NBLK * 4);
    float4*   coeff    = (float4*)alloc((size_t)N * 16);
    float*    wself    = (float*)alloc((size_t)N * 4);
    int2*     epack    = (int2*)alloc((size_t)E * 8);
    _Float16* Wt1      = (_Float16*)alloc(128 * 128 * 2);
    _Float16* Wt2      = (_Float16*)alloc(128 * 128 * 2);
    _Float16* Wt3      = (_Float16*)alloc(128 * 64 * 2);
    _Float16* bufH     = (_Float16*)alloc((size_t)N * 128 * 2);  // GEMM out / gather src
    _Float16* actH     = (_Float16*)alloc((size_t)N * 128 * 2);  // agg out / next GEMM in
    (void)ws_size; (void)n_in;

    size_t zero_bytes = (size_t)((char*)rowptr - (char*)degi);
    hipMemsetAsync(degi, 0, zero_bytes, stream);

    convert_w_all<<<160, 256, 0, stream>>>(W1, W2, W3, Wt1, Wt2, Wt3);

    deg_count_kernel<<<(E + 255) / 256, 256, 0, stream>>>(row, degi, E);
    scan_block_kernel<<<NBLK, 256, 0, stream>>>(degi, rowptr, blocksum, p1, p2, coeff, wself, N);
    scan_tops_kernel<<<1, 128, 0, stream>>>(blocksum, blockoff, NBLK);
    scan_add_kernel<<<(N + 255) / 256, 256, 0, stream>>>(rowptr, blockoff, N);
    fill_edges_kernel<<<8 * FILL_C, 256, 0, stream>>>(row, col, rowptr, cursor, coeff,
                                                      epack, E, N, shift);

    float* out = (float*)d_out;
    int aggGrid = (N + 3) / 4;
    int gemmGrid = (N + 63) / 64;
    // layer 1
    gemm_mfma<128, float><<<gemmGrid, 256, 0, stream>>>(x, Wt1, bufH, N);
    agg128_kernel<<<aggGrid, 256, 0, stream>>>((const __half2*)bufH, rowptr, epack, wself,
                                               b1, (__half2*)actH, N);
    // layer 2
    gemm_mfma<128, _Float16><<<gemmGrid, 256, 0, stream>>>(actH, Wt2, bufH, N);
    agg128_kernel<<<aggGrid, 256, 0, stream>>>((const __half2*)bufH, rowptr, epack, wself,
                                               b2, (__half2*)actH, N);
    // layer 3 (D_OUT=64, no relu)
    gemm_mfma<64, _Float16><<<gemmGrid, 256, 0, stream>>>(actH, Wt3, bufH, N);
    agg64_kernel<<<aggGrid, 256, 0, stream>>>((const __half*)bufH, rowptr, epack, wself,
                                              b3, out, N);
}

// Round 5
// 507.181 us; speedup vs baseline: 1.0728x; 1.0728x over previous
//
#include <hip/hip_runtime.h>
#include <hip/hip_fp16.h>
#include <math.h>
#include <type_traits>

typedef _Float16 half8 __attribute__((ext_vector_type(8)));
typedef float floatx4 __attribute__((ext_vector_type(4)));

// ---------------- degree count ----------------
__global__ void deg_count_kernel(const int* __restrict__ row, int* __restrict__ degi, int E) {
    int g = blockIdx.x * blockDim.x + threadIdx.x;
    if (g < E) atomicAdd(&degi[row[g]], 1);
}

// ---------------- per-node GSO coefficient helper ----------------
__device__ __forceinline__ float pow_z(float d, float e) {
    float p = powf(d, e);
    return isinf(p) ? 0.0f : p;   // reference zeroes inf from 0**negative
}

__device__ __forceinline__ void gso_coeff(float deg, const float* __restrict__ p1,
                                          const float* __restrict__ p2,
                                          float4* cf, float* ws) {
    float m1a = p1[0], m2a = p1[1], m3a = p1[2], e1a = p1[3], e2a = p1[4], e3a = p1[5], aa = p1[6];
    float m1b = p2[0], m2b = p2[1], m3b = p2[2], e1b = p2[3], e2b = p2[4], e3b = p2[5], ab = p2[6];
    float d1 = deg + aa, d2 = deg + ab;
    float pa1 = pow_z(d1, e1a), pa2 = pow_z(d1, e2a), pa3 = pow_z(d1, e3a);
    float pb1 = pow_z(d2, e1b), pb2 = pow_z(d2, e2b), pb3 = pow_z(d2, e3b);
    *cf = make_float4(m2a * pa2, pa3, m2b * pb2, pb3);
    *ws = m1a * pa1 + m2a * pa2 * pa3 + m3a
        + m1b * pb1 + m2b * pb2 * pb3 + m3b;
}

// ---------------- fused: block scan of degrees + GSO coefficients ----------------
__global__ void scan_block_kernel(const int* __restrict__ degi, int* __restrict__ rowptr,
                                  int* __restrict__ blocksum,
                                  const float* __restrict__ p1, const float* __restrict__ p2,
                                  float4* __restrict__ coeff, float* __restrict__ wself, int n) {
    __shared__ int sums[256];
    int tid = threadIdx.x;
    int base = blockIdx.x * 1024 + tid * 4;
    int d0 = (base + 0 < n) ? degi[base + 0] : 0;
    int d1 = (base + 1 < n) ? degi[base + 1] : 0;
    int d2 = (base + 2 < n) ? degi[base + 2] : 0;
    int d3 = (base + 3 < n) ? degi[base + 3] : 0;
    int s0 = d0, s1 = s0 + d1, s2 = s1 + d2, s3 = s2 + d3;
    sums[tid] = s3;
    __syncthreads();
    for (int off = 1; off < 256; off <<= 1) {
        int v = (tid >= off) ? sums[tid - off] : 0;
        __syncthreads();
        sums[tid] += v;
        __syncthreads();
    }
    int excl = sums[tid] - s3;
    if (base + 0 < n) rowptr[base + 1] = excl + s0;
    if (base + 1 < n) rowptr[base + 2] = excl + s1;
    if (base + 2 < n) rowptr[base + 3] = excl + s2;
    if (base + 3 < n) rowptr[base + 4] = excl + s3;
    if (tid == 255) blocksum[blockIdx.x] = sums[255];
    int dd[4] = {d0, d1, d2, d3};
#pragma unroll
    for (int u = 0; u < 4; ++u) {
        if (base + u < n) {
            float4 cf; float ws;
            gso_coeff((float)dd[u], p1, p2, &cf, &ws);
            coeff[base + u] = cf;
            wself[base + u] = ws;
        }
    }
}

__global__ void scan_tops_kernel(const int* __restrict__ blocksum, int* __restrict__ blockoff, int nb) {
    __shared__ int s[128];
    int tid = threadIdx.x;
    int v = (tid < nb) ? blocksum[tid] : 0;
    s[tid] = v;
    __syncthreads();
    for (int off = 1; off < 128; off <<= 1) {
        int u = (tid >= off) ? s[tid - off] : 0;
        __syncthreads();
        s[tid] += u;
        __syncthreads();
    }
    if (tid < nb) blockoff[tid] = s[tid] - v;
}

__global__ void scan_add_kernel(int* __restrict__ rowptr, const int* __restrict__ blockoff, int n) {
    int g = blockIdx.x * blockDim.x + threadIdx.x;
    if (g == 0) rowptr[0] = 0;
    if (g < n) rowptr[g + 1] += blockoff[g >> 10];
}

// ---------------- pass B: radix partition edges by row-bucket ----------------
// One block per 4096 edges. Bucket = row >> shift (<=256 buckets). Edges are
// staged bucket-sorted in LDS, then copied out bucket-contiguous (coalesced
// within segments) to epack_mid at positions claimed by ONE global atomic per
// bucket per block. Packed entry: .x = col | (rlocal << 20), .y = w bits.
__global__ __launch_bounds__(256) void partition_kernel(
        const int* __restrict__ row, const int* __restrict__ col,
        const int* __restrict__ rowptr, int* __restrict__ gcur,
        const float4* __restrict__ coeff, int2* __restrict__ epack_mid,
        int E, int shift, int NB) {
    __shared__ int scnt[256], sofs[256], scur[256], gslot[256];
    __shared__ int2 sdata[4096];
    __shared__ unsigned short sbkt[4096];

    int tid = threadIdx.x;
    int base = blockIdx.x * 4096;
    scnt[tid] = 0;
    __syncthreads();

    int epk[16]; float ew[16]; int eb[16];
#pragma unroll
    for (int u = 0; u < 16; ++u) {
        int e = base + u * 256 + tid;
        eb[u] = -1;
        if (e < E) {
            int r = row[e], c = col[e];
            int b = r >> shift;
            eb[u] = b;
            atomicAdd(&scnt[b], 1);
            float4 cr = coeff[r], cc = coeff[c];
            ew[u] = cr.x * cc.y + cr.z * cc.w;
            epk[u] = c | ((r & ((1 << shift) - 1)) << 20);
        }
    }
    __syncthreads();
    // exclusive scan of scnt
    sofs[tid] = scnt[tid];
    __syncthreads();
    for (int off = 1; off < 256; off <<= 1) {
        int v = (tid >= off) ? sofs[tid - off] : 0;
        __syncthreads();
        sofs[tid] += v;
        __syncthreads();
    }
    int excl = sofs[tid] - scnt[tid];
    sofs[tid] = excl;            // own-slot overwrite, no cross-thread read
    scur[tid] = excl;
    if (tid < NB && scnt[tid] > 0)
        gslot[tid] = rowptr[tid << shift] + atomicAdd(&gcur[tid], scnt[tid]);
    __syncthreads();
    // stage bucket-sorted into LDS
#pragma unroll
    for (int u = 0; u < 16; ++u) {
        if (eb[u] >= 0) {
            int idx = atomicAdd(&scur[eb[u]], 1);
            sdata[idx] = make_int2(epk[u], __float_as_int(ew[u]));
            sbkt[idx] = (unsigned short)eb[u];
        }
    }
    __syncthreads();
    // coalesced copy out
    int cntR = min(4096, E - base);
    for (int i = tid; i < cntR; i += 256) {
        int b = sbkt[i];
        epack_mid[gslot[b] + (i - sofs[b])] = sdata[i];
    }
}

// ---------------- pass C: within-bucket CSR placement ----------------
// One block per bucket. The bucket's CSR slice (~64KB) is owned by this block
// only -> scattered 8B stores stay in one XCD's L2 until lines fill completely.
__global__ __launch_bounds__(256) void bucket_sort_kernel(
        const int* __restrict__ rowptr, const int2* __restrict__ epack_mid,
        int2* __restrict__ epack, int N, int shift) {
    __shared__ int lcur[4096];   // per-row absolute cursor (rows_per_bucket <= 4096)
    int b = blockIdx.x;
    int tid = threadIdx.x;
    int rows = 1 << shift;
    int row0 = b << shift;
    for (int j = tid; j < rows; j += 256) {
        int rid = row0 + j;
        if (rid < N) lcur[j] = rowptr[rid];
    }
    __syncthreads();
    int slice0 = rowptr[row0];
    int slice1 = rowptr[min(row0 + rows, N)];
    for (int i = slice0 + tid; i < slice1; i += 256) {
        int2 p = epack_mid[i];
        int rl = ((unsigned)p.x) >> 20;
        int pos = atomicAdd(&lcur[rl], 1);
        epack[pos] = make_int2(p.x & 0xFFFFF, p.y);
    }
}

// ---------------- W convert + transpose (one launch) ----------------
__global__ void convert_w_all(const float* __restrict__ W1, const float* __restrict__ W2,
                              const float* __restrict__ W3, _Float16* __restrict__ Wt1,
                              _Float16* __restrict__ Wt2, _Float16* __restrict__ Wt3) {
    int g = blockIdx.x * blockDim.x + threadIdx.x;
    if (g < 16384) {
        int k = g >> 7, n = g & 127;
        Wt1[n * 128 + k] = (_Float16)W1[g];
    } else if (g < 32768) {
        int h = g - 16384; int k = h >> 7, n = h & 127;
        Wt2[n * 128 + k] = (_Float16)W2[h];
    } else if (g < 40960) {
        int h = g - 32768; int k = h >> 6, n = h & 63;
        Wt3[n * 128 + k] = (_Float16)W3[h];
    }
}

// ---------------- MFMA GEMM: A[n x 128] @ W[128 x TN] -> C[n x TN] fp16 ----------------
template<int TN, typename AT>
__global__ __launch_bounds__(256) void gemm_mfma(const AT* __restrict__ A,
        const _Float16* __restrict__ Wt,   // [TN][128] pre-transposed fp16
        _Float16* __restrict__ C, int n) {
    constexpr int K = 128;
    constexpr int TM = 64;
    constexpr int LDK = K + 8;
    __shared__ _Float16 As[TM][LDK];
    __shared__ _Float16 Bs[TN][LDK];

    int tid = threadIdx.x;
    int wave = tid >> 6, lane = tid & 63;
    int q = lane >> 4, t = lane & 15;
    int rowbase = blockIdx.x * TM;

    if constexpr (std::is_same<AT, float>::value) {
        for (int i = tid; i < TM * K / 4; i += 256) {
            int r = i >> 5;
            int kc = (i & 31) * 4;
            int rr = rowbase + r;
            float4 v = make_float4(0.f, 0.f, 0.f, 0.f);
            if (rr < n) v = *(const float4*)&A[(size_t)rr * K + kc];
            As[r][kc + 0] = (_Float16)v.x;
            As[r][kc + 1] = (_Float16)v.y;
            As[r][kc + 2] = (_Float16)v.z;
            As[r][kc + 3] = (_Float16)v.w;
        }
    } else {
        for (int i = tid; i < TM * K / 8; i += 256) {
            int r = i >> 4;
            int kc = (i & 15) * 8;
            int rr = rowbase + r;
            uint4 v = make_uint4(0u, 0u, 0u, 0u);
            if (rr < n) v = *(const uint4*)&A[(size_t)rr * K + kc];
            *(uint4*)&As[r][kc] = v;
        }
    }
    for (int i = tid; i < TN * K / 8; i += 256) {
        int nr = i >> 4;
        int kc = (i & 15) * 8;
        *(uint4*)&Bs[nr][kc] = *(const uint4*)&Wt[(size_t)nr * K + kc];
    }
    __syncthreads();

    int m0 = wave * 16;
    floatx4 acc[TN / 16];
#pragma unroll
    for (int nt = 0; nt < TN / 16; ++nt) acc[nt] = (floatx4){0.f, 0.f, 0.f, 0.f};

#pragma unroll
    for (int kk = 0; kk < K; kk += 32) {
        half8 a = *(const half8*)&As[m0 + t][kk + q * 8];
#pragma unroll
        for (int nt = 0; nt < TN / 16; ++nt) {
            half8 b = *(const half8*)&Bs[nt * 16 + t][kk + q * 8];
            acc[nt] = __builtin_amdgcn_mfma_f32_16x16x32_f16(a, b, acc[nt], 0, 0, 0);
        }
    }

#pragma unroll
    for (int nt = 0; nt < TN / 16; ++nt) {
#pragma unroll
        for (int r = 0; r < 4; ++r) {
            int rr = rowbase + m0 + q * 4 + r;
            if (rr < n) C[(size_t)rr * TN + nt * 16 + t] = (_Float16)acc[nt][r];
        }
    }
}

// ---------------- CSR aggregation, D=128, fp16 in / fp16 out, relu ----------------
__global__ __launch_bounds__(256) void agg128_kernel(const __half2* __restrict__ H,
        const int* __restrict__ rowptr, const int2* __restrict__ epack,
        const float* __restrict__ wself, const float* __restrict__ bias,
        __half2* __restrict__ out, int n) {
    int node = blockIdx.x * 4 + (threadIdx.x >> 6);
    if (node >= n) return;
    int lane = threadIdx.x & 63;
    int start = rowptr[node], end = rowptr[node + 1];
    float ws = wself[node];
    float2 hs = __half22float2(H[(size_t)node * 64 + lane]);
    float ax = ws * hs.x, ay = ws * hs.y;
    int e = start;
    for (; e + 8 <= end; e += 8) {
        int2 p0 = epack[e + 0], p1 = epack[e + 1], p2 = epack[e + 2], p3 = epack[e + 3];
        int2 p4 = epack[e + 4], p5 = epack[e + 5], p6 = epack[e + 6], p7 = epack[e + 7];
        __half2 h0 = H[(size_t)p0.x * 64 + lane];
        __half2 h1 = H[(size_t)p1.x * 64 + lane];
        __half2 h2 = H[(size_t)p2.x * 64 + lane];
        __half2 h3 = H[(size_t)p3.x * 64 + lane];
        __half2 h4 = H[(size_t)p4.x * 64 + lane];
        __half2 h5 = H[(size_t)p5.x * 64 + lane];
        __half2 h6 = H[(size_t)p6.x * 64 + lane];
        __half2 h7 = H[(size_t)p7.x * 64 + lane];
        float2 f0 = __half22float2(h0), f1 = __half22float2(h1);
        float2 f2 = __half22float2(h2), f3 = __half22float2(h3);
        float2 f4 = __half22float2(h4), f5 = __half22float2(h5);
        float2 f6 = __half22float2(h6), f7 = __half22float2(h7);
        float w0 = __int_as_float(p0.y), w1 = __int_as_float(p1.y);
        float w2 = __int_as_float(p2.y), w3 = __int_as_float(p3.y);
        float w4 = __int_as_float(p4.y), w5 = __int_as_float(p5.y);
        float w6 = __int_as_float(p6.y), w7 = __int_as_float(p7.y);
        ax += w0 * f0.x + w1 * f1.x + w2 * f2.x + w3 * f3.x
            + w4 * f4.x + w5 * f5.x + w6 * f6.x + w7 * f7.x;
        ay += w0 * f0.y + w1 * f1.y + w2 * f2.y + w3 * f3.y
            + w4 * f4.y + w5 * f5.y + w6 * f6.y + w7 * f7.y;
    }
    for (; e < end; ++e) {
        int2 pe = epack[e];
        float w = __int_as_float(pe.y);
        float2 f = __half22float2(H[(size_t)pe.x * 64 + lane]);
        ax += w * f.x; ay += w * f.y;
    }
    float2 b = *(const float2*)&bias[2 * lane];
    float vx = fmaxf(ax + b.x, 0.0f);
    float vy = fmaxf(ay + b.y, 0.0f);
    out[(size_t)node * 64 + lane] = __floats2half2_rn(vx, vy);
}

// ---------------- CSR aggregation, D=64, fp16 in / fp32 out, no relu ----------------
__global__ __launch_bounds__(256) void agg64_kernel(const __half* __restrict__ H,
        const int* __restrict__ rowptr, const int2* __restrict__ epack,
        const float* __restrict__ wself, const float* __restrict__ bias,
        float* __restrict__ out, int n) {
    int node = blockIdx.x * 4 + (threadIdx.x >> 6);
    if (node >= n) return;
    int lane = threadIdx.x & 63;
    int start = rowptr[node], end = rowptr[node + 1];
    float ws = wself[node];
    float acc = ws * __half2float(H[(size_t)node * 64 + lane]);
    int e = start;
    for (; e + 8 <= end; e += 8) {
        int2 p0 = epack[e + 0], p1 = epack[e + 1], p2 = epack[e + 2], p3 = epack[e + 3];
        int2 p4 = epack[e + 4], p5 = epack[e + 5], p6 = epack[e + 6], p7 = epack[e + 7];
        float f0 = __half2float(H[(size_t)p0.x * 64 + lane]);
        float f1 = __half2float(H[(size_t)p1.x * 64 + lane]);
        float f2 = __half2float(H[(size_t)p2.x * 64 + lane]);
        float f3 = __half2float(H[(size_t)p3.x * 64 + lane]);
        float f4 = __half2float(H[(size_t)p4.x * 64 + lane]);
        float f5 = __half2float(H[(size_t)p5.x * 64 + lane]);
        float f6 = __half2float(H[(size_t)p6.x * 64 + lane]);
        float f7 = __half2float(H[(size_t)p7.x * 64 + lane]);
        acc += __int_as_float(p0.y) * f0 + __int_as_float(p1.y) * f1
             + __int_as_float(p2.y) * f2 + __int_as_float(p3.y) * f3
             + __int_as_float(p4.y) * f4 + __int_as_float(p5.y) * f5
             + __int_as_float(p6.y) * f6 + __int_as_float(p7.y) * f7;
    }
    for (; e < end; ++e) {
        int2 pe = epack[e];
        acc += __int_as_float(pe.y) * __half2float(H[(size_t)pe.x * 64 + lane]);
    }
    out[(size_t)node * 64 + lane] = acc + bias[lane];
}

// ---------------- launch ----------------
extern "C" void kernel_launch(void* const* d_in, const int* in_sizes, int n_in,
                              void* d_out, int out_size, void* d_ws, size_t ws_size,
                              hipStream_t stream) {
    const float* x  = (const float*)d_in[0];
    const int*   ei = (const int*)d_in[1];
    const float* W1 = (const float*)d_in[2];
    const float* b1 = (const float*)d_in[3];
    const float* W2 = (const float*)d_in[4];
    const float* b2 = (const float*)d_in[5];
    const float* W3 = (const float*)d_in[6];
    const float* b3 = (const float*)d_in[7];
    const float* p1 = (const float*)d_in[8];
    const float* p2 = (const float*)d_in[9];

    const int N = in_sizes[0] / 128;
    const int E = in_sizes[1] / 2;
    const int* row = ei;
    const int* col = ei + E;

    // bucket shift: smallest s with ((N-1)>>s)+1 <= 256  (N=100000 -> 9, 196 buckets)
    int shift = 0;
    while ((((N - 1) >> shift) + 1) > 256) shift++;
    const int NB = ((N - 1) >> shift) + 1;

    char* p = (char*)d_ws;
    auto alloc = [&](size_t bytes) -> void* {
        void* q = (void*)p;
        p += (bytes + 255) & ~(size_t)255;
        return q;
    };
    int*      degi      = (int*)alloc((size_t)N * 4);
    int*      gcur      = (int*)alloc(256 * 4);          // contiguous with degi for one memset
    int*      rowptr    = (int*)alloc((size_t)(N + 1) * 4);
    const int NBLK      = (N + 1023) / 1024;
    int*      blocksum  = (int*)alloc((size_t)NBLK * 4);
    int*      blockoff  = (int*)alloc((size_t)NBLK * 4);
    float4*   coeff     = (float4*)alloc((size_t)N * 16);
    float*    wself     = (float*)alloc((size_t)N * 4);
    int2*     epack_mid = (int2*)alloc((size_t)E * 8);
    int2*     epack     = (int2*)alloc((size_t)E * 8);
    _Float16* Wt1       = (_Float16*)alloc(128 * 128 * 2);
    _Float16* Wt2       = (_Float16*)alloc(128 * 128 * 2);
    _Float16* Wt3       = (_Float16*)alloc(128 * 64 * 2);
    _Float16* bufH      = (_Float16*)alloc((size_t)N * 128 * 2);
    _Float16* actH      = (_Float16*)alloc((size_t)N * 128 * 2);
    (void)ws_size; (void)n_in;

    size_t zero_bytes = (size_t)((char*)rowptr - (char*)degi);
    hipMemsetAsync(degi, 0, zero_bytes, stream);

    convert_w_all<<<160, 256, 0, stream>>>(W1, W2, W3, Wt1, Wt2, Wt3);

    deg_count_kernel<<<(E + 255) / 256, 256, 0, stream>>>(row, degi, E);
    scan_block_kernel<<<NBLK, 256, 0, stream>>>(degi, rowptr, blocksum, p1, p2, coeff, wself, N);
    scan_tops_kernel<<<1, 128, 0, stream>>>(blocksum, blockoff, NBLK);
    scan_add_kernel<<<(N + 255) / 256, 256, 0, stream>>>(rowptr, blockoff, N);
    partition_kernel<<<(E + 4095) / 4096, 256, 0, stream>>>(row, col, rowptr, gcur, coeff,
                                                            epack_mid, E, shift, NB);
    bucket_sort_kernel<<<NB, 256, 0, stream>>>(rowptr, epack_mid, epack, N, shift);

    float* out = (float*)d_out;
    int aggGrid = (N + 3) / 4;
    int gemmGrid = (N + 63) / 64;
    // layer 1
    gemm_mfma<128, float><<<gemmGrid, 256, 0, stream>>>(x, Wt1, bufH, N);
    agg128_kernel<<<aggGrid, 256, 0, stream>>>((const __half2*)bufH, rowptr, epack, wself,
                                               b1, (__half2*)actH, N);
    // layer 2
    gemm_mfma<128, _Float16><<<gemmGrid, 256, 0, stream>>>(actH, Wt2, bufH, N);
    agg128_kernel<<<aggGrid, 256, 0, stream>>>((const __half2*)bufH, rowptr, epack, wself,
                                               b2, (__half2*)actH, N);
    // layer 3 (D_OUT=64, no relu)
    gemm_mfma<64, _Float16><<<gemmGrid, 256, 0, stream>>>(actH, Wt3, bufH, N);
    agg64_kernel<<<aggGrid, 256, 0, stream>>>((const __half*)bufH, rowptr, epack, wself,
                                              b3, out, N);
}